// Round 6
// baseline (395.771 us; speedup 1.0000x reference)
//
#include <hip/hip_runtime.h>
#include <math.h>

#define NQ     2048
#define DMODEL 512
#define NH     8
#define DHD    64
#define MEMT   512
#define KVT    2560
#define QSCALE 0.125f
#define NEGF   (-1e30f)
#define NBLK   512

typedef unsigned short u16;
typedef __bf16 bf16x8 __attribute__((ext_vector_type(8)));
typedef float  f32x4  __attribute__((ext_vector_type(4)));
typedef u16    u16x8  __attribute__((ext_vector_type(8)));
typedef u16    u16x4  __attribute__((ext_vector_type(4)));

__device__ __forceinline__ u16 f2bf(float f) {
    union { float f; unsigned u; } v; v.f = f;
    unsigned r = (v.u + 0x7FFFu + ((v.u >> 16) & 1u)) >> 16;
    return (u16)r;
}

// Poison-tolerant grid barrier: every block release-stores a magic tag into its
// flag; block 0 scans all flags, then release-stores the tag into flags[NBLK];
// all blocks acquire-spin on it. Agent-scope atomics -> LLC, cross-XCD safe.
// Works for ANY initial flag contents (only equality-to-tag matters).
__device__ __forceinline__ void gridbar(int* flags, int tag) {
    __syncthreads();
    int bid = blockIdx.x, tid = threadIdx.x;
    if (tid == 0)
        __hip_atomic_store(&flags[bid], tag, __ATOMIC_RELEASE, __HIP_MEMORY_SCOPE_AGENT);
    if (bid == 0) {
        __shared__ int nd;
        for (;;) {
            if (tid == 0) nd = 0;
            __syncthreads();
            int bad = 0;
            for (int j = tid; j < NBLK; j += 256)
                if (__hip_atomic_load(&flags[j], __ATOMIC_ACQUIRE, __HIP_MEMORY_SCOPE_AGENT) != tag) { bad = 1; break; }
            if (bad) nd = 1;
            __syncthreads();
            if (nd == 0) break;
            __builtin_amdgcn_s_sleep(2);
        }
        if (tid == 0)
            __hip_atomic_store(&flags[NBLK], tag, __ATOMIC_RELEASE, __HIP_MEMORY_SCOPE_AGENT);
    } else {
        if (tid == 0) {
            while (__hip_atomic_load(&flags[NBLK], __ATOMIC_ACQUIRE, __HIP_MEMORY_SCOPE_AGENT) != tag)
                __builtin_amdgcn_s_sleep(2);
        }
    }
    __syncthreads();
}

#define LOADK(BK, BEP, C0)                                                     \
  _Pragma("unroll")                                                            \
  for (int t = 0; t < 4; ++t) {                                                \
    const u16* kr = kb + ((h * KVT + (C0) + t * 16 + lr) * DHD + lg * 8);      \
    BK[t][0] = __builtin_bit_cast(bf16x8, *(const u16x8*)kr);                  \
    BK[t][1] = __builtin_bit_cast(bf16x8, *(const u16x8*)(kr + 32));           \
    BEP[t] = ep[(C0) + t * 16 + lr];                                           \
  }

#define DO_CHUNK(C0, BK, BEP, PREF, NBK, NBEP)                                 \
  {                                                                            \
    bf16x8 bV[4][2];                                                           \
    _Pragma("unroll")                                                          \
    for (int t = 0; t < 4; ++t) {                                              \
      const u16* vr = vtb + ((h * DHD + t * 16 + lr) * KVT + (C0) + lg * 8);   \
      bV[t][0] = __builtin_bit_cast(bf16x8, *(const u16x8*)vr);                \
      bV[t][1] = __builtin_bit_cast(bf16x8, *(const u16x8*)(vr + 32));         \
    }                                                                          \
    f32x4 s[4];                                                                \
    _Pragma("unroll")                                                          \
    for (int t = 0; t < 4; ++t) {                                              \
      f32x4 z = {0.f, 0.f, 0.f, 0.f};                                          \
      s[t] = __builtin_amdgcn_mfma_f32_16x16x32_bf16(aQ[0], BK[t][0], z, 0, 0, 0); \
      s[t] = __builtin_amdgcn_mfma_f32_16x16x32_bf16(aQ[1], BK[t][1], s[t], 0, 0, 0); \
    }                                                                          \
    if (PREF) { LOADK(NBK, NBEP, (C0) + 64) }                                  \
    float rmax[4] = {NEGF, NEGF, NEGF, NEGF};                                  \
    _Pragma("unroll")                                                          \
    for (int t = 0; t < 4; ++t) {                                              \
      int key = (C0) + t * 16 + lr;                                            \
      int ek = BEP[t];                                                         \
      _Pragma("unroll")                                                        \
      for (int r = 0; r < 4; ++r) {                                            \
        bool vld = (key <= qpos[r]) && (ek == epq[r]);                         \
        float sv = vld ? s[t][r] * QSCALE : NEGF;                              \
        s[t][r] = sv;                                                          \
        rmax[r] = fmaxf(rmax[r], sv);                                          \
      }                                                                        \
    }                                                                          \
    _Pragma("unroll")                                                          \
    for (int mm = 1; mm < 16; mm <<= 1) {                                      \
      _Pragma("unroll")                                                        \
      for (int r = 0; r < 4; ++r)                                              \
        rmax[r] = fmaxf(rmax[r], __shfl_xor(rmax[r], mm, 64));                 \
    }                                                                          \
    float alpha[4];                                                            \
    _Pragma("unroll")                                                          \
    for (int r = 0; r < 4; ++r) {                                              \
      float mn = fmaxf(mrun[r], rmax[r]);                                      \
      alpha[r] = __expf(mrun[r] - mn);                                         \
      mrun[r] = mn;                                                            \
      lsum[r] *= alpha[r];                                                     \
    }                                                                          \
    _Pragma("unroll")                                                          \
    for (int t = 0; t < 4; ++t)                                                \
      _Pragma("unroll")                                                        \
      for (int r = 0; r < 4; ++r) o[t][r] *= alpha[r];                         \
    float psum[4] = {0.f, 0.f, 0.f, 0.f};                                      \
    _Pragma("unroll")                                                          \
    for (int t = 0; t < 4; ++t) {                                              \
      _Pragma("unroll")                                                        \
      for (int r = 0; r < 4; ++r) {                                            \
        float sv = s[t][r];                                                    \
        float p = (sv <= -1e29f) ? 0.f : __expf(sv - mrun[r]);                 \
        psum[r] += p;                                                          \
        int qq = lg * 4 + r;                                                   \
        int kk2 = t * 16 + lr;                                                 \
        pl[qq * 64 + (kk2 ^ ((qq & 7) << 3))] = f2bf(p);                       \
      }                                                                        \
    }                                                                          \
    _Pragma("unroll")                                                          \
    for (int mm = 1; mm < 16; mm <<= 1) {                                      \
      _Pragma("unroll")                                                        \
      for (int r = 0; r < 4; ++r) psum[r] += __shfl_xor(psum[r], mm, 64);      \
    }                                                                          \
    _Pragma("unroll")                                                          \
    for (int r = 0; r < 4; ++r) lsum[r] += psum[r];                            \
    bf16x8 aP[2];                                                              \
    {                                                                          \
      int sw = (lr & 7) << 3;                                                  \
      aP[0] = __builtin_bit_cast(bf16x8, *(const u16x8*)&pl[lr * 64 + ((lg * 8) ^ sw)]);        \
      aP[1] = __builtin_bit_cast(bf16x8, *(const u16x8*)&pl[lr * 64 + ((32 + lg * 8) ^ sw)]);   \
    }                                                                          \
    _Pragma("unroll")                                                          \
    for (int t = 0; t < 4; ++t) {                                              \
      o[t] = __builtin_amdgcn_mfma_f32_16x16x32_bf16(aP[0], bV[t][0], o[t], 0, 0, 0); \
      o[t] = __builtin_amdgcn_mfma_f32_16x16x32_bf16(aP[1], bV[t][1], o[t], 0, 0, 0); \
    }                                                                          \
  }

__global__ __launch_bounds__(256, 2) void mega(
    const float* __restrict__ x, const float* __restrict__ cache_k,
    const float* __restrict__ cache_v, const int* __restrict__ ep,
    const float* __restrict__ Wq, const float* __restrict__ Wkv,
    const float* __restrict__ Wg, const float* __restrict__ Wo,
    u16* __restrict__ xb, u16* __restrict__ Wt, u16* __restrict__ Wot,
    u16* __restrict__ qb, u16* __restrict__ kb, u16* __restrict__ vtb,
    u16* __restrict__ attnb, float* __restrict__ gates,
    float2* __restrict__ cs, int* __restrict__ flags,
    float* __restrict__ outf)
{
    __shared__ char smem[17408];
    const int bid = blockIdx.x, tid = threadIdx.x;
    const int w = tid >> 6, lane = tid & 63;
    const int lr = lane & 15, lg = lane >> 4;

    // ================= Phase A: independent prep =================
    // units: [0,64) x->bf16 | [64,320) W transposes | [320,384) gates
    //        [384,512) RoPE table | [512,576) cache-V transpose
    for (int unit = bid; unit < 576; unit += NBLK) {
        if (unit < 64) {
            int base4 = unit * 4096;
#pragma unroll
            for (int u = 0; u < 16; ++u) {
                int i4 = base4 + u * 256 + tid;
                float4 v = ((const float4*)x)[i4];
                u16x4 o4 = { f2bf(v.x), f2bf(v.y), f2bf(v.z), f2bf(v.w) };
                *(u16x4*)&xb[i4 * 4] = o4;
            }
        } else if (unit < 320) {
            __syncthreads();
            float (*tile)[65] = (float(*)[65])smem;
            int tt = unit - 64;
            bool isQKV = (tt < 192);
            int tc, tr;
            if (isQKV) { tc = tt % 24; tr = tt / 24; }
            else       { tt -= 192; tc = tt & 7; tr = tt >> 3; }
            int rr = tid >> 4, c4 = (tid & 15) * 4;
#pragma unroll
            for (int u = 0; u < 4; ++u) {
                int row = u * 16 + rr;
                int k = tr * 64 + row, c = tc * 64 + c4;
                float4 v;
                if (isQKV) v = (c < 512) ? *(const float4*)&Wq[k * 512 + c]
                                         : *(const float4*)&Wkv[k * 1024 + (c - 512)];
                else       v = *(const float4*)&Wo[k * 512 + c];
                tile[row][c4 + 0] = v.x; tile[row][c4 + 1] = v.y;
                tile[row][c4 + 2] = v.z; tile[row][c4 + 3] = v.w;
            }
            __syncthreads();
#pragma unroll
            for (int u = 0; u < 4; ++u) {
                int trow = u * 16 + rr;
                u16x4 o4;
#pragma unroll
                for (int i = 0; i < 4; ++i) o4[i] = f2bf(tile[c4 + i][trow]);
                int tg = tc * 64 + trow, kg = tr * 64 + c4;
                if (isQKV) *(u16x4*)&Wt[tg * 512 + kg] = o4;
                else       *(u16x4*)&Wot[tg * 512 + kg] = o4;
            }
        } else if (unit < 384) {
            int t = (unit - 320) * 256 + tid;
            int n = t >> 3, hh = t & 7;
            float acc = 0.f;
            for (int k = 0; k < DMODEL; k += 4) {
                float4 xv = *(const float4*)&x[n * DMODEL + k];
                acc += xv.x * Wg[(k + 0) * NH + hh] + xv.y * Wg[(k + 1) * NH + hh]
                     + xv.z * Wg[(k + 2) * NH + hh] + xv.w * Wg[(k + 3) * NH + hh];
            }
            gates[hh * NQ + n] = 1.f / (1.f + __expf(-acc));
        } else if (unit < 512) {
            int tu = unit - 384;
#pragma unroll
            for (int kk = 0; kk < 3; ++kk) {
                int e = kk * 256 + tid;
                if (e < 640) {
                    int idx = tu * 640 + e;
                    int pos = idx >> 5, j = idx & 31;
                    float invf = exp2f(-(float)j * (13.287712379549449f / 32.f));
                    float ss, sc;
                    sincosf((float)pos * invf, &ss, &sc);
                    cs[idx] = make_float2(sc, ss);
                }
            }
        } else {
            __syncthreads();
            u16 (*tile)[66] = (u16(*)[66])smem;
            int uu = unit - 512;
            int tb = uu & 7, h = uu >> 3;
            int rr = tid >> 4, c4 = (tid & 15) * 4;
            int r0 = tb * 64;
#pragma unroll
            for (int u = 0; u < 4; ++u) {
                int row = u * 16 + rr;
                float4 v = *(const float4*)&cache_v[(h * MEMT + r0 + row) * DHD + c4];
                tile[row][c4 + 0] = f2bf(v.x); tile[row][c4 + 1] = f2bf(v.y);
                tile[row][c4 + 2] = f2bf(v.z); tile[row][c4 + 3] = f2bf(v.w);
            }
            __syncthreads();
#pragma unroll
            for (int u = 0; u < 4; ++u) {
                int d = u * 16 + rr;
                u16x4 o4 = { tile[c4 + 0][d], tile[c4 + 1][d], tile[c4 + 2][d], tile[c4 + 3][d] };
                *(u16x4*)&vtb[(h * DHD + d) * KVT + r0 + c4] = o4;
            }
        }
    }
    gridbar(flags, 0x7A5A0001);

    // ================= Phase B: QKV GEMM (+RoPE epi, +V transpose) + cache-K RoPE
    for (int u2 = bid; u2 < 832; u2 += NBLK) {
        if (u2 < 768) {
            int bx = u2 % 24, by = u2 / 24;
            int rowbase = by * 64 + (w >> 1) * 32;
            int colbase = bx * 64 + (w & 1) * 16;
            f32x4 acc[2][2];
#pragma unroll
            for (int i = 0; i < 2; ++i)
#pragma unroll
                for (int j = 0; j < 2; ++j) { f32x4 z = {0.f,0.f,0.f,0.f}; acc[i][j] = z; }
            const u16* a0 = xb + (rowbase + lr) * 512 + lg * 8;
            const u16* a1 = a0 + 16 * 512;
            const u16* b0 = Wt + (colbase + lr) * 512 + lg * 8;
            const u16* b1 = b0 + 32 * 512;
#pragma unroll 4
            for (int k0 = 0; k0 < 512; k0 += 32) {
                bf16x8 fa0 = __builtin_bit_cast(bf16x8, *(const u16x8*)(a0 + k0));
                bf16x8 fa1 = __builtin_bit_cast(bf16x8, *(const u16x8*)(a1 + k0));
                bf16x8 fb0 = __builtin_bit_cast(bf16x8, *(const u16x8*)(b0 + k0));
                bf16x8 fb1 = __builtin_bit_cast(bf16x8, *(const u16x8*)(b1 + k0));
                acc[0][0] = __builtin_amdgcn_mfma_f32_16x16x32_bf16(fa0, fb0, acc[0][0], 0, 0, 0);
                acc[0][1] = __builtin_amdgcn_mfma_f32_16x16x32_bf16(fa0, fb1, acc[0][1], 0, 0, 0);
                acc[1][0] = __builtin_amdgcn_mfma_f32_16x16x32_bf16(fa1, fb0, acc[1][0], 0, 0, 0);
                acc[1][1] = __builtin_amdgcn_mfma_f32_16x16x32_bf16(fa1, fb1, acc[1][1], 0, 0, 0);
            }
            int j = (colbase & 63) + lr;     // 0..31
            int region = bx >> 3;            // 0=q, 1=k_new, 2=v
            int h = bx & 7;
            if (region == 2) {
                // stage into LDS, write vT transposed (coalesced)
                __syncthreads();
                u16 (*vtile)[72] = (u16(*)[72])smem;
#pragma unroll
                for (int rt = 0; rt < 2; ++rt)
#pragma unroll
                    for (int r = 0; r < 4; ++r) {
                        int rl = (w >> 1) * 32 + rt * 16 + lg * 4 + r;
                        vtile[rl][j]      = f2bf(acc[rt][0][r]);
                        vtile[rl][j + 32] = f2bf(acc[rt][1][r]);
                    }
                __syncthreads();
                int rr = tid >> 4, c4 = (tid & 15) * 4;
#pragma unroll
                for (int u = 0; u < 4; ++u) {
                    int d = u * 16 + rr;
                    u16x4 o4 = { vtile[c4 + 0][d], vtile[c4 + 1][d], vtile[c4 + 2][d], vtile[c4 + 3][d] };
                    *(u16x4*)&vtb[(h * DHD + d) * KVT + 512 + by * 64 + c4] = o4;
                }
            } else {
#pragma unroll
                for (int rt = 0; rt < 2; ++rt)
#pragma unroll
                    for (int r = 0; r < 4; ++r) {
                        int n = rowbase + rt * 16 + lg * 4 + r;
                        float a = acc[rt][0][r], b = acc[rt][1][r];
                        float2 csv = cs[(512 + n) * 32 + j];
                        u16 e0 = f2bf(a * csv.x - b * csv.y);
                        u16 e1 = f2bf(b * csv.x + a * csv.y);
                        if (region == 0) {
                            qb[(h * NQ + n) * DHD + j]      = e0;
                            qb[(h * NQ + n) * DHD + 32 + j] = e1;
                        } else {
                            kb[(h * KVT + 512 + n) * DHD + j]      = e0;
                            kb[(h * KVT + 512 + n) * DHD + 32 + j] = e1;
                        }
                    }
            }
        } else {
            int uu = u2 - 768;
            int r0 = (uu & 7) * 64, h = uu >> 3;
#pragma unroll
            for (int u = 0; u < 8; ++u) {
                int idx = u * 256 + tid;
                int row = idx >> 5, j = idx & 31;
                int r = r0 + row;
                float a = cache_k[(h * MEMT + r) * DHD + j];
                float b = cache_k[(h * MEMT + r) * DHD + 32 + j];
                float2 csv = cs[r * 32 + j];
                kb[(h * KVT + r) * DHD + j]      = f2bf(a * csv.x - b * csv.y);
                kb[(h * KVT + r) * DHD + 32 + j] = f2bf(b * csv.x + a * csv.y);
            }
        }
    }
    gridbar(flags, 0x7A5A0002);

    // ================= Phase C: split-KV MFMA flash attention =================
    {
        u16* plds = (u16*)smem;                       // [4][1024]
        float* o_lf = (float*)(smem + 8192);          // [2][16][68]
        float* ml_lf = (float*)(smem + 16896);        // [2][2][16]
        int h = bid >> 6;
        int q0 = (bid & 63) * 32;
        int qsub = w & 1, kvh = w >> 1;
        int qbase = q0 + qsub * 16;
        u16* pl = plds + w * 1024;

        bf16x8 aQ[2];
        {
            const u16* qrow = qb + ((h * NQ + qbase + lr) * DHD + lg * 8);
            aQ[0] = __builtin_bit_cast(bf16x8, *(const u16x8*)qrow);
            aQ[1] = __builtin_bit_cast(bf16x8, *(const u16x8*)(qrow + 32));
        }
        int qpos[4], epq[4];
        float gq[4];
#pragma unroll
        for (int r = 0; r < 4; ++r) {
            int q = qbase + lg * 4 + r;
            qpos[r] = 512 + q;
            epq[r] = ep[512 + q];
            gq[r] = gates[h * NQ + q];
        }
        f32x4 o[4];
        float mrun[4], lsum[4];
#pragma unroll
        for (int t = 0; t < 4; ++t) { f32x4 z = {0.f,0.f,0.f,0.f}; o[t] = z; }
#pragma unroll
        for (int r = 0; r < 4; ++r) { mrun[r] = NEGF; lsum[r] = 0.f; }

        int c_lo = q0 & ~511;
        int nch = (544 + (q0 & 511) + 63) >> 6;
        int n0 = nch >> 1;
        int my_n = kvh ? (nch - n0) : n0;
        int c0 = c_lo + (kvh ? (n0 << 6) : 0);

        bf16x8 bKA[4][2], bKB[4][2];
        int epA[4], epB[4];
        LOADK(bKA, epA, c0)
        int ci = 0;
        while (true) {
            bool more = (ci + 1 < my_n);
            DO_CHUNK(c0, bKA, epA, more, bKB, epB)
            ++ci; c0 += 64;
            if (!more) break;
            bool more2 = (ci + 1 < my_n);
            DO_CHUNK(c0, bKB, epB, more2, bKA, epA)
            ++ci; c0 += 64;
            if (!more2) break;
        }

        if (kvh == 1) {
#pragma unroll
            for (int r = 0; r < 4; ++r) {
                ml_lf[(qsub * 2 + 0) * 16 + lg * 4 + r] = mrun[r];
                ml_lf[(qsub * 2 + 1) * 16 + lg * 4 + r] = lsum[r];
            }
#pragma unroll
            for (int t = 0; t < 4; ++t)
#pragma unroll
                for (int r = 0; r < 4; ++r)
                    o_lf[(qsub * 16 + lg * 4 + r) * 68 + t * 16 + lr] = o[t][r];
        }
        __syncthreads();
        if (kvh == 0) {
#pragma unroll
            for (int r = 0; r < 4; ++r) {
                int row = lg * 4 + r;
                float m1 = ml_lf[(qsub * 2 + 0) * 16 + row];
                float l1 = ml_lf[(qsub * 2 + 1) * 16 + row];
                float m0 = mrun[r], l0 = lsum[r];
                float mm2 = fmaxf(m0, m1);
                float f0 = (m0 <= -1e29f) ? 0.f : __expf(m0 - mm2);
                float f1 = (m1 <= -1e29f) ? 0.f : __expf(m1 - mm2);
                float lt = l0 * f0 + l1 * f1;
                float inv = gq[r] / lt;
                int q = qbase + row;
#pragma unroll
                for (int t = 0; t < 4; ++t) {
                    float o1 = o_lf[(qsub * 16 + row) * 68 + t * 16 + lr];
                    attnb[q * DMODEL + h * DHD + t * 16 + lr] =
                        f2bf((o[t][r] * f0 + o1 * f1) * inv);
                }
            }
        }
    }
    gridbar(flags, 0x7A5A0003);

    // ================= Phase D: out = attn @ Wo (32x64 tiles, 512 units) =====
    if (bid < 512) {
        int bx = bid & 7, by = bid >> 3;
        int rowbase = by * 32 + (w >> 1) * 16;
        int colbase = bx * 64 + (w & 1) * 16;
        f32x4 acc0 = {0.f,0.f,0.f,0.f}, acc1 = {0.f,0.f,0.f,0.f};
        const u16* a0 = attnb + (rowbase + lr) * 512 + lg * 8;
        const u16* b0 = Wot + (colbase + lr) * 512 + lg * 8;
        const u16* b1 = b0 + 32 * 512;
#pragma unroll 4
        for (int k0 = 0; k0 < 512; k0 += 32) {
            bf16x8 fa  = __builtin_bit_cast(bf16x8, *(const u16x8*)(a0 + k0));
            bf16x8 fb0 = __builtin_bit_cast(bf16x8, *(const u16x8*)(b0 + k0));
            bf16x8 fb1 = __builtin_bit_cast(bf16x8, *(const u16x8*)(b1 + k0));
            acc0 = __builtin_amdgcn_mfma_f32_16x16x32_bf16(fa, fb0, acc0, 0, 0, 0);
            acc1 = __builtin_amdgcn_mfma_f32_16x16x32_bf16(fa, fb1, acc1, 0, 0, 0);
        }
#pragma unroll
        for (int r = 0; r < 4; ++r) {
            int n = rowbase + lg * 4 + r;
            outf[n * DMODEL + colbase + lr]      = acc0[r];
            outf[n * DMODEL + colbase + 32 + lr] = acc1[r];
        }
    }
}

// ---------------------------------------------------------------------------
extern "C" void kernel_launch(void* const* d_in, const int* in_sizes, int n_in,
                              void* d_out, int out_size, void* d_ws, size_t ws_size,
                              hipStream_t stream) {
    const float* x       = (const float*)d_in[0];
    const float* cache_k = (const float*)d_in[1];
    const float* cache_v = (const float*)d_in[2];
    const int*   ep      = (const int*)  d_in[3];
    const float* Wq      = (const float*)d_in[4];
    const float* Wkv     = (const float*)d_in[5];
    const float* Wg      = (const float*)d_in[6];
    const float* Wo      = (const float*)d_in[7];
    float* out = (float*)d_out;

    u16* u = (u16*)d_ws;
    u16* x_bf    = u;                          // 1048576
    u16* Wt      = x_bf + 1048576;             // 786432
    u16* Wot     = Wt + 786432;                // 262144
    u16* q_bf    = Wot + 262144;               // 1048576
    u16* k_bf    = q_bf + 1048576;             // 1310720
    u16* vT      = k_bf + 1310720;             // 1310720
    u16* attn_bf = vT + 1310720;               // 1048576
    float*  gatesw = (float*)(attn_bf + 1048576);   // 16384 f32
    float2* cs     = (float2*)(gatesw + 16384);     // 81920 float2
    int*    flags  = (int*)(cs + 81920);            // 513 int

    mega<<<NBLK, 256, 0, stream>>>(x, cache_k, cache_v, ep, Wq, Wkv, Wg, Wo,
                                   x_bf, Wt, Wot, q_bf, k_bf, vT, attn_bf,
                                   gatesw, cs, flags, out);
}

// Round 8
// 249.068 us; speedup vs baseline: 1.5890x; 1.5890x over previous
//
#include <hip/hip_runtime.h>
#include <math.h>

#define NQ     2048
#define DMODEL 512
#define NH     8
#define DHD    64
#define MEMT   512
#define KVT    2560
#define QSCALE 0.125f
#define NEGF   (-1e30f)
#define NBLK   512

typedef unsigned short u16;
typedef __bf16 bf16x8 __attribute__((ext_vector_type(8)));
typedef float  f32x4  __attribute__((ext_vector_type(4)));
typedef u16    u16x8  __attribute__((ext_vector_type(8)));
typedef u16    u16x4  __attribute__((ext_vector_type(4)));
typedef u16    u16x2  __attribute__((ext_vector_type(2)));

__device__ __forceinline__ u16 f2bf(float f) {
    union { float f; unsigned u; } v; v.f = f;
    unsigned r = (v.u + 0x7FFFu + ((v.u >> 16) & 1u)) >> 16;
    return (u16)r;
}

// Grid barrier, poison-tolerant. KEY FIX vs round 6: spin with RELAXED
// agent-scope loads (coherent LLC loads, NO cache invalidation), one acquire
// fence at the end. Periodic fence inside the spin guards against staleness.
__device__ __forceinline__ void gridbar(int* flags, int tag) {
    __syncthreads();
    int bid = blockIdx.x, tid = threadIdx.x;
    if (tid == 0)
        __hip_atomic_store(&flags[bid], tag, __ATOMIC_RELEASE, __HIP_MEMORY_SCOPE_AGENT);
    if (bid == 0) {
        __shared__ int nd;
        int iter = 0;
        for (;;) {
            if (tid == 0) nd = 0;
            __syncthreads();
            int bad = 0;
            for (int j = tid; j < NBLK; j += 256)
                if (__hip_atomic_load(&flags[j], __ATOMIC_RELAXED, __HIP_MEMORY_SCOPE_AGENT) != tag) { bad = 1; break; }
            if (bad) nd = 1;
            __syncthreads();
            if (nd == 0) break;
            if (((++iter) & 63) == 0)
                __builtin_amdgcn_fence(__ATOMIC_ACQUIRE, "agent");
            __builtin_amdgcn_s_sleep(8);
        }
        if (tid == 0)
            __hip_atomic_store(&flags[NBLK], tag, __ATOMIC_RELEASE, __HIP_MEMORY_SCOPE_AGENT);
    } else {
        if (tid == 0) {
            int iter = 0;
            while (__hip_atomic_load(&flags[NBLK], __ATOMIC_RELAXED, __HIP_MEMORY_SCOPE_AGENT) != tag) {
                if (((++iter) & 63) == 0)
                    __builtin_amdgcn_fence(__ATOMIC_ACQUIRE, "agent");
                __builtin_amdgcn_s_sleep(8);
            }
        }
    }
    __syncthreads();
    __builtin_amdgcn_fence(__ATOMIC_ACQUIRE, "agent");
}

#define LOADK(BK, BEP, C0)                                                     \
  _Pragma("unroll")                                                            \
  for (int t = 0; t < 4; ++t) {                                                \
    const u16* kr = kb + ((h * KVT + (C0) + t * 16 + lr) * DHD + lg * 8);      \
    BK[t][0] = __builtin_bit_cast(bf16x8, *(const u16x8*)kr);                  \
    BK[t][1] = __builtin_bit_cast(bf16x8, *(const u16x8*)(kr + 32));           \
    BEP[t] = ep[(C0) + t * 16 + lr];                                           \
  }

#define DO_CHUNK(C0, BK, BEP, PREF, NBK, NBEP)                                 \
  {                                                                            \
    bf16x8 bV[4][2];                                                           \
    _Pragma("unroll")                                                          \
    for (int t = 0; t < 4; ++t) {                                              \
      const u16* vr = vtb + ((h * DHD + t * 16 + lr) * KVT + (C0) + lg * 8);   \
      bV[t][0] = __builtin_bit_cast(bf16x8, *(const u16x8*)vr);                \
      bV[t][1] = __builtin_bit_cast(bf16x8, *(const u16x8*)(vr + 32));         \
    }                                                                          \
    f32x4 s[4];                                                                \
    _Pragma("unroll")                                                          \
    for (int t = 0; t < 4; ++t) {                                              \
      f32x4 z = {0.f, 0.f, 0.f, 0.f};                                          \
      s[t] = __builtin_amdgcn_mfma_f32_16x16x32_bf16(aQ[0], BK[t][0], z, 0, 0, 0); \
      s[t] = __builtin_amdgcn_mfma_f32_16x16x32_bf16(aQ[1], BK[t][1], s[t], 0, 0, 0); \
    }                                                                          \
    if (PREF) { LOADK(NBK, NBEP, (C0) + 64) }                                  \
    float rmax[4] = {NEGF, NEGF, NEGF, NEGF};                                  \
    _Pragma("unroll")                                                          \
    for (int t = 0; t < 4; ++t) {                                              \
      int key = (C0) + t * 16 + lr;                                            \
      int ek = BEP[t];                                                         \
      _Pragma("unroll")                                                        \
      for (int r = 0; r < 4; ++r) {                                            \
        bool vld = (key <= qpos[r]) && (ek == epq[r]);                         \
        float sv = vld ? s[t][r] * QSCALE : NEGF;                              \
        s[t][r] = sv;                                                          \
        rmax[r] = fmaxf(rmax[r], sv);                                          \
      }                                                                        \
    }                                                                          \
    _Pragma("unroll")                                                          \
    for (int mm = 1; mm < 16; mm <<= 1) {                                      \
      _Pragma("unroll")                                                        \
      for (int r = 0; r < 4; ++r)                                              \
        rmax[r] = fmaxf(rmax[r], __shfl_xor(rmax[r], mm, 64));                 \
    }                                                                          \
    float alpha[4];                                                            \
    _Pragma("unroll")                                                          \
    for (int r = 0; r < 4; ++r) {                                              \
      float mn = fmaxf(mrun[r], rmax[r]);                                      \
      alpha[r] = __expf(mrun[r] - mn);                                         \
      mrun[r] = mn;                                                            \
      lsum[r] *= alpha[r];                                                     \
    }                                                                          \
    _Pragma("unroll")                                                          \
    for (int t = 0; t < 4; ++t)                                                \
      _Pragma("unroll")                                                        \
      for (int r = 0; r < 4; ++r) o[t][r] *= alpha[r];                         \
    float psum[4] = {0.f, 0.f, 0.f, 0.f};                                      \
    _Pragma("unroll")                                                          \
    for (int t = 0; t < 4; ++t) {                                              \
      _Pragma("unroll")                                                        \
      for (int r = 0; r < 4; ++r) {                                            \
        float sv = s[t][r];                                                    \
        float p = (sv <= -1e29f) ? 0.f : __expf(sv - mrun[r]);                 \
        psum[r] += p;                                                          \
        int qq = lg * 4 + r;                                                   \
        int kk2 = t * 16 + lr;                                                 \
        pl[qq * 64 + (kk2 ^ ((qq & 7) << 3))] = f2bf(p);                       \
      }                                                                        \
    }                                                                          \
    _Pragma("unroll")                                                          \
    for (int mm = 1; mm < 16; mm <<= 1) {                                      \
      _Pragma("unroll")                                                        \
      for (int r = 0; r < 4; ++r) psum[r] += __shfl_xor(psum[r], mm, 64);      \
    }                                                                          \
    _Pragma("unroll")                                                          \
    for (int r = 0; r < 4; ++r) lsum[r] += psum[r];                            \
    bf16x8 aP[2];                                                              \
    {                                                                          \
      int sw = (lr & 7) << 3;                                                  \
      aP[0] = __builtin_bit_cast(bf16x8, *(const u16x8*)&pl[lr * 64 + ((lg * 8) ^ sw)]);        \
      aP[1] = __builtin_bit_cast(bf16x8, *(const u16x8*)&pl[lr * 64 + ((32 + lg * 8) ^ sw)]);   \
    }                                                                          \
    _Pragma("unroll")                                                          \
    for (int t = 0; t < 4; ++t) {                                              \
      o[t] = __builtin_amdgcn_mfma_f32_16x16x32_bf16(aP[0], bV[t][0], o[t], 0, 0, 0); \
      o[t] = __builtin_amdgcn_mfma_f32_16x16x32_bf16(aP[1], bV[t][1], o[t], 0, 0, 0); \
    }                                                                          \
  }

__global__ __launch_bounds__(256, 2) void mega(
    const float* __restrict__ x, const float* __restrict__ cache_k,
    const float* __restrict__ cache_v, const int* __restrict__ ep,
    const float* __restrict__ Wq, const float* __restrict__ Wkv,
    const float* __restrict__ Wg, const float* __restrict__ Wo,
    u16* __restrict__ xb, u16* __restrict__ Wt, u16* __restrict__ Wot,
    u16* __restrict__ qb, u16* __restrict__ kb, u16* __restrict__ vtb,
    u16* __restrict__ attnb, float* __restrict__ gates,
    float2* __restrict__ cs, int* __restrict__ flags,
    float* __restrict__ outf)
{
    __shared__ __attribute__((aligned(16))) char smem[17408];
    const int bid = blockIdx.x, tid = threadIdx.x;
    const int w = tid >> 6, lane = tid & 63;
    const int lr = lane & 15, lg = lane >> 4;

    // ================= Phase A: independent prep (448 units, 1/block) ========
    // [0,32) x->bf16 | [32,288) W transposes | [288,320) gates
    // [320,384) RoPE table | [384,448) cache-V transpose
    if (bid < 32) {
        int base4 = bid * 8192;
#pragma unroll
        for (int u = 0; u < 32; ++u) {
            int i4 = base4 + u * 256 + tid;
            float4 v = ((const float4*)x)[i4];
            u16x4 o4 = { f2bf(v.x), f2bf(v.y), f2bf(v.z), f2bf(v.w) };
            *(u16x4*)&xb[i4 * 4] = o4;
        }
    } else if (bid < 288) {
        float (*tile)[65] = (float(*)[65])smem;
        int tt = bid - 32;
        bool isQKV = (tt < 192);
        int tc, tr;
        if (isQKV) { tc = tt % 24; tr = tt / 24; }
        else       { tt -= 192; tc = tt & 7; tr = tt >> 3; }
        int rr = tid >> 4, c4 = (tid & 15) * 4;
#pragma unroll
        for (int u = 0; u < 4; ++u) {
            int row = u * 16 + rr;
            int k = tr * 64 + row, c = tc * 64 + c4;
            float4 v;
            if (isQKV) v = (c < 512) ? *(const float4*)&Wq[k * 512 + c]
                                     : *(const float4*)&Wkv[k * 1024 + (c - 512)];
            else       v = *(const float4*)&Wo[k * 512 + c];
            tile[row][c4 + 0] = v.x; tile[row][c4 + 1] = v.y;
            tile[row][c4 + 2] = v.z; tile[row][c4 + 3] = v.w;
        }
        __syncthreads();
#pragma unroll
        for (int u = 0; u < 4; ++u) {
            int trow = u * 16 + rr;
            u16x4 o4;
#pragma unroll
            for (int i = 0; i < 4; ++i) o4[i] = f2bf(tile[c4 + i][trow]);
            int tg = tc * 64 + trow, kg = tr * 64 + c4;
            if (isQKV) *(u16x4*)&Wt[tg * 512 + kg] = o4;
            else       *(u16x4*)&Wot[tg * 512 + kg] = o4;
        }
    } else if (bid < 320) {
#pragma unroll
        for (int kk = 0; kk < 2; ++kk) {
            int t = (bid - 288) * 512 + kk * 256 + tid;
            int n = t >> 3, hh = t & 7;
            float acc = 0.f;
            for (int k = 0; k < DMODEL; k += 4) {
                float4 xv = *(const float4*)&x[n * DMODEL + k];
                acc += xv.x * Wg[(k + 0) * NH + hh] + xv.y * Wg[(k + 1) * NH + hh]
                     + xv.z * Wg[(k + 2) * NH + hh] + xv.w * Wg[(k + 3) * NH + hh];
            }
            gates[hh * NQ + n] = 1.f / (1.f + __expf(-acc));
        }
    } else if (bid < 384) {
#pragma unroll
        for (int kk = 0; kk < 5; ++kk) {
            int idx = (bid - 320) * 1280 + kk * 256 + tid;
            int pos = idx >> 5, j = idx & 31;
            float invf = exp2f(-(float)j * (13.287712379549449f / 32.f));
            float ss, sc;
            sincosf((float)pos * invf, &ss, &sc);
            cs[idx] = make_float2(sc, ss);
        }
    } else if (bid < 448) {
        u16 (*tile)[66] = (u16(*)[66])smem;
        int uu = bid - 384;
        int tb = uu & 7, h = uu >> 3;
        int rr = tid >> 4, c4 = (tid & 15) * 4;
        int r0 = tb * 64;
#pragma unroll
        for (int u = 0; u < 4; ++u) {
            int row = u * 16 + rr;
            float4 v = *(const float4*)&cache_v[(h * MEMT + r0 + row) * DHD + c4];
            tile[row][c4 + 0] = f2bf(v.x); tile[row][c4 + 1] = f2bf(v.y);
            tile[row][c4 + 2] = f2bf(v.z); tile[row][c4 + 3] = f2bf(v.w);
        }
        __syncthreads();
#pragma unroll
        for (int u = 0; u < 4; ++u) {
            int d = u * 16 + rr;
            u16x4 o4 = { tile[c4 + 0][d], tile[c4 + 1][d], tile[c4 + 2][d], tile[c4 + 3][d] };
            *(u16x4*)&vtb[(h * DHD + d) * KVT + r0 + c4] = o4;
        }
    }
    gridbar(flags, 0x51A70001);

    // ====== Phase B: QKV GEMM 32x64 tiles (1536 = 3/block) + cache-K RoPE ====
#pragma unroll 1
    for (int it = 0; it < 3; ++it) {
        int u2 = it * NBLK + bid;            // 0..1535
        int bx = u2 % 24, by = u2 / 24;      // by: 0..63 (32-row tiles)
        int rowbase = by * 32;
        int rfrag = rowbase + (w >> 1) * 16;
        int colbase = bx * 64 + (w & 1) * 16;
        f32x4 acc0 = {0.f,0.f,0.f,0.f}, acc1 = {0.f,0.f,0.f,0.f};
        const u16* a0 = xb + (rfrag + lr) * 512 + lg * 8;
        const u16* b0 = Wt + (colbase + lr) * 512 + lg * 8;
        const u16* b1 = b0 + 32 * 512;
#pragma unroll 4
        for (int k0 = 0; k0 < 512; k0 += 32) {
            bf16x8 fa  = __builtin_bit_cast(bf16x8, *(const u16x8*)(a0 + k0));
            bf16x8 fb0 = __builtin_bit_cast(bf16x8, *(const u16x8*)(b0 + k0));
            bf16x8 fb1 = __builtin_bit_cast(bf16x8, *(const u16x8*)(b1 + k0));
            acc0 = __builtin_amdgcn_mfma_f32_16x16x32_bf16(fa, fb0, acc0, 0, 0, 0);
            acc1 = __builtin_amdgcn_mfma_f32_16x16x32_bf16(fa, fb1, acc1, 0, 0, 0);
        }
        int j = (colbase & 63) + lr;         // 0..31
        int region = bx >> 3;                // 0=q, 1=k_new, 2=v
        int h = bx & 7;
        if (region == 2) {
            __syncthreads();
            u16 (*vtile)[73] = (u16(*)[73])smem;
#pragma unroll
            for (int r = 0; r < 4; ++r) {
                int rl = (w >> 1) * 16 + lg * 4 + r;
                vtile[rl][j]      = f2bf(acc0[r]);
                vtile[rl][j + 32] = f2bf(acc1[r]);
            }
            __syncthreads();
            int rr = tid >> 4, c2 = (tid & 15) * 2;
#pragma unroll
            for (int u = 0; u < 4; ++u) {
                int d = u * 16 + rr;
                u16x2 o2 = { vtile[c2][d], vtile[c2 + 1][d] };
                *(u16x2*)&vtb[(h * DHD + d) * KVT + 512 + rowbase + c2] = o2;
            }
        } else {
#pragma unroll
            for (int r = 0; r < 4; ++r) {
                int n = rfrag + lg * 4 + r;
                float a = acc0[r], b = acc1[r];
                float2 csv = cs[(512 + n) * 32 + j];
                u16 e0 = f2bf(a * csv.x - b * csv.y);
                u16 e1 = f2bf(b * csv.x + a * csv.y);
                if (region == 0) {
                    qb[(h * NQ + n) * DHD + j]      = e0;
                    qb[(h * NQ + n) * DHD + 32 + j] = e1;
                } else {
                    kb[(h * KVT + 512 + n) * DHD + j]      = e0;
                    kb[(h * KVT + 512 + n) * DHD + 32 + j] = e1;
                }
            }
        }
    }
    if (bid < 64) {                          // cache-K RoPE (table from phase A)
        int r0 = (bid & 7) * 64, h = bid >> 3;
#pragma unroll
        for (int u = 0; u < 8; ++u) {
            int idx = u * 256 + tid;
            int row = idx >> 5, j = idx & 31;
            int r = r0 + row;
            float a = cache_k[(h * MEMT + r) * DHD + j];
            float b = cache_k[(h * MEMT + r) * DHD + 32 + j];
            float2 csv = cs[r * 32 + j];
            kb[(h * KVT + r) * DHD + j]      = f2bf(a * csv.x - b * csv.y);
            kb[(h * KVT + r) * DHD + 32 + j] = f2bf(b * csv.x + a * csv.y);
        }
    }
    gridbar(flags, 0x51A70002);

    // ================= Phase C: split-KV MFMA flash attention =================
    {
        u16* plds = (u16*)smem;                       // [4][1024]
        float* o_lf = (float*)(smem + 8192);          // [2][16][68]
        float* ml_lf = (float*)(smem + 16896);        // [2][2][16]
        int h = bid >> 6;
        int q0 = (bid & 63) * 32;
        int qsub = w & 1, kvh = w >> 1;
        int qbase = q0 + qsub * 16;
        u16* pl = plds + w * 1024;

        bf16x8 aQ[2];
        {
            const u16* qrow = qb + ((h * NQ + qbase + lr) * DHD + lg * 8);
            aQ[0] = __builtin_bit_cast(bf16x8, *(const u16x8*)qrow);
            aQ[1] = __builtin_bit_cast(bf16x8, *(const u16x8*)(qrow + 32));
        }
        int qpos[4], epq[4];
        float gq[4];
#pragma unroll
        for (int r = 0; r < 4; ++r) {
            int q = qbase + lg * 4 + r;
            qpos[r] = 512 + q;
            epq[r] = ep[512 + q];
            gq[r] = gates[h * NQ + q];
        }
        f32x4 o[4];
        float mrun[4], lsum[4];
#pragma unroll
        for (int t = 0; t < 4; ++t) { f32x4 z = {0.f,0.f,0.f,0.f}; o[t] = z; }
#pragma unroll
        for (int r = 0; r < 4; ++r) { mrun[r] = NEGF; lsum[r] = 0.f; }

        int c_lo = q0 & ~511;
        int nch = (544 + (q0 & 511) + 63) >> 6;
        int n0 = nch >> 1;
        int my_n = kvh ? (nch - n0) : n0;
        int c0 = c_lo + (kvh ? (n0 << 6) : 0);

        bf16x8 bKA[4][2], bKB[4][2];
        int epA[4], epB[4];
        LOADK(bKA, epA, c0)
        int ci = 0;
        while (true) {
            bool more = (ci + 1 < my_n);
            DO_CHUNK(c0, bKA, epA, more, bKB, epB)
            ++ci; c0 += 64;
            if (!more) break;
            bool more2 = (ci + 1 < my_n);
            DO_CHUNK(c0, bKB, epB, more2, bKA, epA)
            ++ci; c0 += 64;
            if (!more2) break;
        }

        if (kvh == 1) {
#pragma unroll
            for (int r = 0; r < 4; ++r) {
                ml_lf[(qsub * 2 + 0) * 16 + lg * 4 + r] = mrun[r];
                ml_lf[(qsub * 2 + 1) * 16 + lg * 4 + r] = lsum[r];
            }
#pragma unroll
            for (int t = 0; t < 4; ++t)
#pragma unroll
                for (int r = 0; r < 4; ++r)
                    o_lf[(qsub * 16 + lg * 4 + r) * 68 + t * 16 + lr] = o[t][r];
        }
        __syncthreads();
        if (kvh == 0) {
#pragma unroll
            for (int r = 0; r < 4; ++r) {
                int row = lg * 4 + r;
                float m1 = ml_lf[(qsub * 2 + 0) * 16 + row];
                float l1 = ml_lf[(qsub * 2 + 1) * 16 + row];
                float m0 = mrun[r], l0 = lsum[r];
                float mm2 = fmaxf(m0, m1);
                float f0 = (m0 <= -1e29f) ? 0.f : __expf(m0 - mm2);
                float f1 = (m1 <= -1e29f) ? 0.f : __expf(m1 - mm2);
                float lt = l0 * f0 + l1 * f1;
                float inv = gq[r] / lt;
                int q = qbase + row;
#pragma unroll
                for (int t = 0; t < 4; ++t) {
                    float o1 = o_lf[(qsub * 16 + row) * 68 + t * 16 + lr];
                    attnb[q * DMODEL + h * DHD + t * 16 + lr] =
                        f2bf((o[t][r] * f0 + o1 * f1) * inv);
                }
            }
        }
    }
    gridbar(flags, 0x51A70003);

    // ================= Phase D: out = attn @ Wo (512 x 32x64 tiles) ==========
    {
        int bx = bid & 7, by = bid >> 3;
        int rowbase = by * 32 + (w >> 1) * 16;
        int colbase = bx * 64 + (w & 1) * 16;
        f32x4 acc0 = {0.f,0.f,0.f,0.f}, acc1 = {0.f,0.f,0.f,0.f};
        const u16* a0 = attnb + (rowbase + lr) * 512 + lg * 8;
        const u16* b0 = Wot + (colbase + lr) * 512 + lg * 8;
        const u16* b1 = b0 + 32 * 512;
#pragma unroll 4
        for (int k0 = 0; k0 < 512; k0 += 32) {
            bf16x8 fa  = __builtin_bit_cast(bf16x8, *(const u16x8*)(a0 + k0));
            bf16x8 fb0 = __builtin_bit_cast(bf16x8, *(const u16x8*)(b0 + k0));
            bf16x8 fb1 = __builtin_bit_cast(bf16x8, *(const u16x8*)(b1 + k0));
            acc0 = __builtin_amdgcn_mfma_f32_16x16x32_bf16(fa, fb0, acc0, 0, 0, 0);
            acc1 = __builtin_amdgcn_mfma_f32_16x16x32_bf16(fa, fb1, acc1, 0, 0, 0);
        }
#pragma unroll
        for (int r = 0; r < 4; ++r) {
            int n = rowbase + lg * 4 + r;
            outf[n * DMODEL + colbase + lr]      = acc0[r];
            outf[n * DMODEL + colbase + 32 + lr] = acc1[r];
        }
    }
}

// ---------------------------------------------------------------------------
extern "C" void kernel_launch(void* const* d_in, const int* in_sizes, int n_in,
                              void* d_out, int out_size, void* d_ws, size_t ws_size,
                              hipStream_t stream) {
    const float* x       = (const float*)d_in[0];
    const float* cache_k = (const float*)d_in[1];
    const float* cache_v = (const float*)d_in[2];
    const int*   ep      = (const int*)  d_in[3];
    const float* Wq      = (const float*)d_in[4];
    const float* Wkv     = (const float*)d_in[5];
    const float* Wg      = (const float*)d_in[6];
    const float* Wo      = (const float*)d_in[7];
    float* out = (float*)d_out;

    u16* u = (u16*)d_ws;
    u16* x_bf    = u;                          // 1048576
    u16* Wt      = x_bf + 1048576;             // 786432
    u16* Wot     = Wt + 786432;                // 262144
    u16* q_bf    = Wot + 262144;               // 1048576
    u16* k_bf    = q_bf + 1048576;             // 1310720
    u16* vT      = k_bf + 1310720;             // 1310720
    u16* attn_bf = vT + 1310720;               // 1048576
    float*  gatesw = (float*)(attn_bf + 1048576);   // 16384 f32
    float2* cs     = (float2*)(gatesw + 16384);     // 81920 float2
    int*    flags  = (int*)(cs + 81920);            // 513 int

    mega<<<NBLK, 256, 0, stream>>>(x, cache_k, cache_v, ep, Wq, Wkv, Wg, Wo,
                                   x_bf, Wt, Wot, q_bf, k_bf, vT, attn_bf,
                                   gatesw, cs, flags, out);
}

// Round 9
// 159.589 us; speedup vs baseline: 2.4799x; 1.5607x over previous
//
#include <hip/hip_runtime.h>
#include <math.h>

#define NQ     2048
#define DMODEL 512
#define NH     8
#define DHD    64
#define MEMT   512
#define KVT    2560
#define QSCALE 0.125f
#define NEGF   (-1e30f)

typedef unsigned short u16;
typedef __bf16 bf16x8 __attribute__((ext_vector_type(8)));
typedef float  f32x4  __attribute__((ext_vector_type(4)));
typedef u16    u16x8  __attribute__((ext_vector_type(8)));
typedef u16    u16x4  __attribute__((ext_vector_type(4)));

__device__ __forceinline__ u16 f2bf(float f) {
    union { float f; unsigned u; } v; v.f = f;
    unsigned r = (v.u + 0x7FFFu + ((v.u >> 16) & 1u)) >> 16;
    return (u16)r;
}

// ---------------------------------------------------------------------------
// prep: [0,32) x->bf16 | [32,288) W transposes | [288,320) gates
//       [320,384) RoPE table | [384,448) cache-V transpose
// ---------------------------------------------------------------------------
__global__ __launch_bounds__(256) void prep(const float* __restrict__ x,
                                            const float* __restrict__ Wq,
                                            const float* __restrict__ Wkv,
                                            const float* __restrict__ Wo,
                                            const float* __restrict__ Wg,
                                            const float* __restrict__ cache_v,
                                            u16* __restrict__ xb,
                                            u16* __restrict__ Wt,
                                            u16* __restrict__ Wot,
                                            float* __restrict__ gates,
                                            float2* __restrict__ cs,
                                            u16* __restrict__ vtb) {
    __shared__ __attribute__((aligned(16))) char smem[17408];
    int bid = blockIdx.x, tid = threadIdx.x;

    if (bid < 32) {                          // x -> bf16
        int base4 = bid * 8192;
#pragma unroll
        for (int u = 0; u < 32; ++u) {
            int i4 = base4 + u * 256 + tid;
            float4 v = ((const float4*)x)[i4];
            u16x4 o4 = { f2bf(v.x), f2bf(v.y), f2bf(v.z), f2bf(v.w) };
            *(u16x4*)&xb[i4 * 4] = o4;
        }
    } else if (bid < 288) {                  // W transposes
        float (*tile)[65] = (float(*)[65])smem;
        int tt = bid - 32;
        bool isQKV = (tt < 192);
        int tc, tr;
        if (isQKV) { tc = tt % 24; tr = tt / 24; }
        else       { tt -= 192; tc = tt & 7; tr = tt >> 3; }
        int rr = tid >> 4, c4 = (tid & 15) * 4;
#pragma unroll
        for (int u = 0; u < 4; ++u) {
            int row = u * 16 + rr;
            int k = tr * 64 + row, c = tc * 64 + c4;
            float4 v;
            if (isQKV) v = (c < 512) ? *(const float4*)&Wq[k * 512 + c]
                                     : *(const float4*)&Wkv[k * 1024 + (c - 512)];
            else       v = *(const float4*)&Wo[k * 512 + c];
            tile[row][c4 + 0] = v.x; tile[row][c4 + 1] = v.y;
            tile[row][c4 + 2] = v.z; tile[row][c4 + 3] = v.w;
        }
        __syncthreads();
#pragma unroll
        for (int u = 0; u < 4; ++u) {
            int trow = u * 16 + rr;
            u16x4 o4;
#pragma unroll
            for (int i = 0; i < 4; ++i) o4[i] = f2bf(tile[c4 + i][trow]);
            int tg = tc * 64 + trow, kg = tr * 64 + c4;
            if (isQKV) *(u16x4*)&Wt[tg * 512 + kg] = o4;
            else       *(u16x4*)&Wot[tg * 512 + kg] = o4;
        }
    } else if (bid < 320) {                  // gates
#pragma unroll
        for (int kk = 0; kk < 2; ++kk) {
            int t = (bid - 288) * 512 + kk * 256 + tid;
            int n = t >> 3, hh = t & 7;
            float acc = 0.f;
            for (int k = 0; k < DMODEL; k += 4) {
                float4 xv = *(const float4*)&x[n * DMODEL + k];
                acc += xv.x * Wg[(k + 0) * NH + hh] + xv.y * Wg[(k + 1) * NH + hh]
                     + xv.z * Wg[(k + 2) * NH + hh] + xv.w * Wg[(k + 3) * NH + hh];
            }
            gates[hh * NQ + n] = 1.f / (1.f + __expf(-acc));
        }
    } else if (bid < 384) {                  // RoPE cos/sin table
#pragma unroll
        for (int kk = 0; kk < 5; ++kk) {
            int idx = (bid - 320) * 1280 + kk * 256 + tid;
            int pos = idx >> 5, j = idx & 31;
            float invf = exp2f(-(float)j * (13.287712379549449f / 32.f));
            float ss, sc;
            sincosf((float)pos * invf, &ss, &sc);
            cs[idx] = make_float2(sc, ss);
        }
    } else {                                 // cache-V transpose -> vtb rows [0,512)
        u16 (*tile)[66] = (u16(*)[66])smem;
        int uu = bid - 384;
        int tb = uu & 7, h = uu >> 3;
        int rr = tid >> 4, c4 = (tid & 15) * 4;
        int r0 = tb * 64;
#pragma unroll
        for (int u = 0; u < 4; ++u) {
            int row = u * 16 + rr;
            float4 v = *(const float4*)&cache_v[(h * MEMT + r0 + row) * DHD + c4];
            tile[row][c4 + 0] = f2bf(v.x); tile[row][c4 + 1] = f2bf(v.y);
            tile[row][c4 + 2] = f2bf(v.z); tile[row][c4 + 3] = f2bf(v.w);
        }
        __syncthreads();
#pragma unroll
        for (int u = 0; u < 4; ++u) {
            int d = u * 16 + rr;
            u16x4 o4 = { tile[c4 + 0][d], tile[c4 + 1][d], tile[c4 + 2][d], tile[c4 + 3][d] };
            *(u16x4*)&vtb[(h * DHD + d) * KVT + r0 + c4] = o4;
        }
    }
}

// ---------------------------------------------------------------------------
// qkv: 768 GEMM tiles (64x64, XCD-swizzled: xcd u&7 owns 3 B-col-blocks) with
// RoPE/v-transpose epilogue, + 64 cache-K RoPE units. 512 blocks, <=2 units.
// ---------------------------------------------------------------------------
__global__ __launch_bounds__(256, 2) void qkv(const u16* __restrict__ xb,
                                              const u16* __restrict__ Wt,
                                              const float2* __restrict__ cs,
                                              const float* __restrict__ cache_k,
                                              u16* __restrict__ qb,
                                              u16* __restrict__ kb,
                                              u16* __restrict__ vtb) {
    __shared__ __attribute__((aligned(16))) u16 vtile[64][66];
    const int bid = blockIdx.x, tid = threadIdx.x;
    const int w = tid >> 6, lane = tid & 63;
    const int lr = lane & 15, lg = lane >> 4;

#pragma unroll 1
    for (int pass = 0; pass < 2; ++pass) {
        int u2 = pass * 512 + bid;
        if (u2 >= 832) break;
        if (u2 < 768) {
            int i = u2 >> 3;
            int bx = (u2 & 7) * 3 + (i >> 5);   // same-XCD blocks share bx range
            int by = i & 31;
            int rowbase = by * 64 + (w >> 1) * 32;
            int colbase = bx * 64 + (w & 1) * 16;
            f32x4 acc[2][2];
#pragma unroll
            for (int a = 0; a < 2; ++a)
#pragma unroll
                for (int b = 0; b < 2; ++b) { f32x4 z = {0.f,0.f,0.f,0.f}; acc[a][b] = z; }
            const u16* a0 = xb + (rowbase + lr) * 512 + lg * 8;
            const u16* a1 = a0 + 16 * 512;
            const u16* b0 = Wt + (colbase + lr) * 512 + lg * 8;
            const u16* b1 = b0 + 32 * 512;
#pragma unroll 4
            for (int k0 = 0; k0 < 512; k0 += 32) {
                bf16x8 fa0 = __builtin_bit_cast(bf16x8, *(const u16x8*)(a0 + k0));
                bf16x8 fa1 = __builtin_bit_cast(bf16x8, *(const u16x8*)(a1 + k0));
                bf16x8 fb0 = __builtin_bit_cast(bf16x8, *(const u16x8*)(b0 + k0));
                bf16x8 fb1 = __builtin_bit_cast(bf16x8, *(const u16x8*)(b1 + k0));
                acc[0][0] = __builtin_amdgcn_mfma_f32_16x16x32_bf16(fa0, fb0, acc[0][0], 0, 0, 0);
                acc[0][1] = __builtin_amdgcn_mfma_f32_16x16x32_bf16(fa0, fb1, acc[0][1], 0, 0, 0);
                acc[1][0] = __builtin_amdgcn_mfma_f32_16x16x32_bf16(fa1, fb0, acc[1][0], 0, 0, 0);
                acc[1][1] = __builtin_amdgcn_mfma_f32_16x16x32_bf16(fa1, fb1, acc[1][1], 0, 0, 0);
            }
            int j = (colbase & 63) + lr;        // 0..31
            int region = bx >> 3;               // 0=q, 1=k_new, 2=v
            int h = bx & 7;
            if (region == 2) {
                __syncthreads();
#pragma unroll
                for (int rt = 0; rt < 2; ++rt)
#pragma unroll
                    for (int r = 0; r < 4; ++r) {
                        int rl = (w >> 1) * 32 + rt * 16 + lg * 4 + r;
                        vtile[rl][j]      = f2bf(acc[rt][0][r]);
                        vtile[rl][j + 32] = f2bf(acc[rt][1][r]);
                    }
                __syncthreads();
                int rr = tid >> 4, c4 = (tid & 15) * 4;
#pragma unroll
                for (int u = 0; u < 4; ++u) {
                    int d = u * 16 + rr;
                    u16x4 o4 = { vtile[c4 + 0][d], vtile[c4 + 1][d], vtile[c4 + 2][d], vtile[c4 + 3][d] };
                    *(u16x4*)&vtb[(h * DHD + d) * KVT + 512 + by * 64 + c4] = o4;
                }
            } else {
#pragma unroll
                for (int rt = 0; rt < 2; ++rt)
#pragma unroll
                    for (int r = 0; r < 4; ++r) {
                        int n = rowbase + rt * 16 + lg * 4 + r;
                        float a = acc[rt][0][r], b = acc[rt][1][r];
                        float2 csv = cs[(512 + n) * 32 + j];
                        u16 e0 = f2bf(a * csv.x - b * csv.y);
                        u16 e1 = f2bf(b * csv.x + a * csv.y);
                        if (region == 0) {
                            qb[(h * NQ + n) * DHD + j]      = e0;
                            qb[(h * NQ + n) * DHD + 32 + j] = e1;
                        } else {
                            kb[(h * KVT + 512 + n) * DHD + j]      = e0;
                            kb[(h * KVT + 512 + n) * DHD + 32 + j] = e1;
                        }
                    }
            }
        } else {                                // cache-K RoPE (table from prep)
            int uu = u2 - 768;
            int r0 = (uu & 7) * 64, h = uu >> 3;
#pragma unroll
            for (int u = 0; u < 8; ++u) {
                int idx = u * 256 + tid;
                int row = idx >> 5, j = idx & 31;
                int r = r0 + row;
                float a = cache_k[(h * MEMT + r) * DHD + j];
                float b = cache_k[(h * MEMT + r) * DHD + 32 + j];
                float2 csv = cs[r * 32 + j];
                kb[(h * KVT + r) * DHD + j]      = f2bf(a * csv.x - b * csv.y);
                kb[(h * KVT + r) * DHD + 32 + j] = f2bf(b * csv.x + a * csv.y);
            }
        }
    }
}

// ---------------------------------------------------------------------------
// Split-KV MFMA flash attention. head = bid&7 -> each XCD owns one head,
// so its K/V (~640 KB) stays L2-resident across that XCD's 64 blocks.
// ---------------------------------------------------------------------------
#define LOADK(BK, BEP, C0)                                                     \
  _Pragma("unroll")                                                            \
  for (int t = 0; t < 4; ++t) {                                                \
    const u16* kr = kb + ((h * KVT + (C0) + t * 16 + lr) * DHD + lg * 8);      \
    BK[t][0] = __builtin_bit_cast(bf16x8, *(const u16x8*)kr);                  \
    BK[t][1] = __builtin_bit_cast(bf16x8, *(const u16x8*)(kr + 32));           \
    BEP[t] = ep[(C0) + t * 16 + lr];                                           \
  }

#define DO_CHUNK(C0, BK, BEP, PREF, NBK, NBEP)                                 \
  {                                                                            \
    bf16x8 bV[4][2];                                                           \
    _Pragma("unroll")                                                          \
    for (int t = 0; t < 4; ++t) {                                              \
      const u16* vr = vtb + ((h * DHD + t * 16 + lr) * KVT + (C0) + lg * 8);   \
      bV[t][0] = __builtin_bit_cast(bf16x8, *(const u16x8*)vr);                \
      bV[t][1] = __builtin_bit_cast(bf16x8, *(const u16x8*)(vr + 32));         \
    }                                                                          \
    f32x4 s[4];                                                                \
    _Pragma("unroll")                                                          \
    for (int t = 0; t < 4; ++t) {                                              \
      f32x4 z = {0.f, 0.f, 0.f, 0.f};                                          \
      s[t] = __builtin_amdgcn_mfma_f32_16x16x32_bf16(aQ[0], BK[t][0], z, 0, 0, 0); \
      s[t] = __builtin_amdgcn_mfma_f32_16x16x32_bf16(aQ[1], BK[t][1], s[t], 0, 0, 0); \
    }                                                                          \
    if (PREF) { LOADK(NBK, NBEP, (C0) + 64) }                                  \
    float rmax[4] = {NEGF, NEGF, NEGF, NEGF};                                  \
    _Pragma("unroll")                                                          \
    for (int t = 0; t < 4; ++t) {                                              \
      int key = (C0) + t * 16 + lr;                                            \
      int ek = BEP[t];                                                         \
      _Pragma("unroll")                                                        \
      for (int r = 0; r < 4; ++r) {                                            \
        bool vld = (key <= qpos[r]) && (ek == epq[r]);                         \
        float sv = vld ? s[t][r] * QSCALE : NEGF;                              \
        s[t][r] = sv;                                                          \
        rmax[r] = fmaxf(rmax[r], sv);                                          \
      }                                                                        \
    }                                                                          \
    _Pragma("unroll")                                                          \
    for (int mm = 1; mm < 16; mm <<= 1) {                                      \
      _Pragma("unroll")                                                        \
      for (int r = 0; r < 4; ++r)                                              \
        rmax[r] = fmaxf(rmax[r], __shfl_xor(rmax[r], mm, 64));                 \
    }                                                                          \
    float alpha[4];                                                            \
    _Pragma("unroll")                                                          \
    for (int r = 0; r < 4; ++r) {                                              \
      float mn = fmaxf(mrun[r], rmax[r]);                                      \
      alpha[r] = __expf(mrun[r] - mn);                                         \
      mrun[r] = mn;                                                            \
      lsum[r] *= alpha[r];                                                     \
    }                                                                          \
    _Pragma("unroll")                                                          \
    for (int t = 0; t < 4; ++t)                                                \
      _Pragma("unroll")                                                        \
      for (int r = 0; r < 4; ++r) o[t][r] *= alpha[r];                         \
    float psum[4] = {0.f, 0.f, 0.f, 0.f};                                      \
    _Pragma("unroll")                                                          \
    for (int t = 0; t < 4; ++t) {                                              \
      _Pragma("unroll")                                                        \
      for (int r = 0; r < 4; ++r) {                                            \
        float sv = s[t][r];                                                    \
        float p = (sv <= -1e29f) ? 0.f : __expf(sv - mrun[r]);                 \
        psum[r] += p;                                                          \
        int qq = lg * 4 + r;                                                   \
        int kk2 = t * 16 + lr;                                                 \
        pl[qq * 64 + (kk2 ^ ((qq & 7) << 3))] = f2bf(p);                       \
      }                                                                        \
    }                                                                          \
    _Pragma("unroll")                                                          \
    for (int mm = 1; mm < 16; mm <<= 1) {                                      \
      _Pragma("unroll")                                                        \
      for (int r = 0; r < 4; ++r) psum[r] += __shfl_xor(psum[r], mm, 64);      \
    }                                                                          \
    _Pragma("unroll")                                                          \
    for (int r = 0; r < 4; ++r) lsum[r] += psum[r];                            \
    bf16x8 aP[2];                                                              \
    {                                                                          \
      int sw = (lr & 7) << 3;                                                  \
      aP[0] = __builtin_bit_cast(bf16x8, *(const u16x8*)&pl[lr * 64 + ((lg * 8) ^ sw)]);        \
      aP[1] = __builtin_bit_cast(bf16x8, *(const u16x8*)&pl[lr * 64 + ((32 + lg * 8) ^ sw)]);   \
    }                                                                          \
    _Pragma("unroll")                                                          \
    for (int t = 0; t < 4; ++t) {                                              \
      o[t] = __builtin_amdgcn_mfma_f32_16x16x32_bf16(aP[0], bV[t][0], o[t], 0, 0, 0); \
      o[t] = __builtin_amdgcn_mfma_f32_16x16x32_bf16(aP[1], bV[t][1], o[t], 0, 0, 0); \
    }                                                                          \
  }

__global__ __launch_bounds__(256, 2) void attn_mfma(const u16* __restrict__ qb,
                                                    const u16* __restrict__ kb,
                                                    const u16* __restrict__ vtb,
                                                    const float* __restrict__ gates,
                                                    const int* __restrict__ ep,
                                                    u16* __restrict__ outp) {
    __shared__ u16 plds[4][16 * 64];
    __shared__ float o_l[2][16][68];
    __shared__ float ml_l[2][2][16];

    int bid = blockIdx.x;
    int h = bid & 7;                         // XCD-local head
    int q0 = (bid >> 3) * 32;
    int tid = threadIdx.x;
    int w = tid >> 6, lane = tid & 63;
    int lr = lane & 15, lg = lane >> 4;
    int qsub = w & 1, kvh = w >> 1;
    int qbase = q0 + qsub * 16;
    u16* pl = plds[w];

    bf16x8 aQ[2];
    {
        const u16* qrow = qb + ((h * NQ + qbase + lr) * DHD + lg * 8);
        aQ[0] = __builtin_bit_cast(bf16x8, *(const u16x8*)qrow);
        aQ[1] = __builtin_bit_cast(bf16x8, *(const u16x8*)(qrow + 32));
    }

    int qpos[4], epq[4];
    float gq[4];
#pragma unroll
    for (int r = 0; r < 4; ++r) {
        int q = qbase + lg * 4 + r;
        qpos[r] = 512 + q;
        epq[r] = ep[512 + q];
        gq[r] = gates[h * NQ + q];
    }

    f32x4 o[4];
    float mrun[4], lsum[4];
#pragma unroll
    for (int t = 0; t < 4; ++t) { f32x4 z = {0.f,0.f,0.f,0.f}; o[t] = z; }
#pragma unroll
    for (int r = 0; r < 4; ++r) { mrun[r] = NEGF; lsum[r] = 0.f; }

    int c_lo = q0 & ~511;
    int nch = (544 + (q0 & 511) + 63) >> 6;
    int n0 = nch >> 1;
    int my_n = kvh ? (nch - n0) : n0;
    int c0 = c_lo + (kvh ? (n0 << 6) : 0);

    bf16x8 bKA[4][2], bKB[4][2];
    int epA[4], epB[4];

    LOADK(bKA, epA, c0)
    int ci = 0;
    while (true) {
        bool more = (ci + 1 < my_n);
        DO_CHUNK(c0, bKA, epA, more, bKB, epB)
        ++ci; c0 += 64;
        if (!more) break;
        bool more2 = (ci + 1 < my_n);
        DO_CHUNK(c0, bKB, epB, more2, bKA, epA)
        ++ci; c0 += 64;
        if (!more2) break;
    }

    if (kvh == 1) {
#pragma unroll
        for (int r = 0; r < 4; ++r) {
            ml_l[qsub][0][lg * 4 + r] = mrun[r];
            ml_l[qsub][1][lg * 4 + r] = lsum[r];
        }
#pragma unroll
        for (int t = 0; t < 4; ++t)
#pragma unroll
            for (int r = 0; r < 4; ++r)
                o_l[qsub][lg * 4 + r][t * 16 + lr] = o[t][r];
    }
    __syncthreads();
    if (kvh == 0) {
#pragma unroll
        for (int r = 0; r < 4; ++r) {
            int row = lg * 4 + r;
            float m1 = ml_l[qsub][0][row], l1 = ml_l[qsub][1][row];
            float m0 = mrun[r], l0 = lsum[r];
            float mm2 = fmaxf(m0, m1);
            float f0 = (m0 <= -1e29f) ? 0.f : __expf(m0 - mm2);
            float f1 = (m1 <= -1e29f) ? 0.f : __expf(m1 - mm2);
            float lt = l0 * f0 + l1 * f1;
            float inv = gq[r] / lt;
            int q = qbase + row;
#pragma unroll
            for (int t = 0; t < 4; ++t) {
                float o1 = o_l[qsub][row][t * 16 + lr];
                outp[q * DMODEL + h * DHD + t * 16 + lr] =
                    f2bf((o[t][r] * f0 + o1 * f1) * inv);
            }
        }
    }
}

// ---------------------------------------------------------------------------
// out = attn @ Wot. 512 x (32x64) tiles; bx = bid&7 -> Wot col-block per XCD.
// ---------------------------------------------------------------------------
__global__ __launch_bounds__(256, 2) void outgemm(const u16* __restrict__ attnb,
                                                  const u16* __restrict__ Wot,
                                                  float* __restrict__ outf) {
    int bid = blockIdx.x, tid = threadIdx.x;
    int w = tid >> 6, lane = tid & 63;
    int lr = lane & 15, lg = lane >> 4;
    int bx = bid & 7, by = bid >> 3;
    int rowbase = by * 32 + (w >> 1) * 16;
    int colbase = bx * 64 + (w & 1) * 16;
    f32x4 acc0 = {0.f,0.f,0.f,0.f}, acc1 = {0.f,0.f,0.f,0.f};
    const u16* a0 = attnb + (rowbase + lr) * 512 + lg * 8;
    const u16* b0 = Wot + (colbase + lr) * 512 + lg * 8;
    const u16* b1 = b0 + 32 * 512;
#pragma unroll 4
    for (int k0 = 0; k0 < 512; k0 += 32) {
        bf16x8 fa  = __builtin_bit_cast(bf16x8, *(const u16x8*)(a0 + k0));
        bf16x8 fb0 = __builtin_bit_cast(bf16x8, *(const u16x8*)(b0 + k0));
        bf16x8 fb1 = __builtin_bit_cast(bf16x8, *(const u16x8*)(b1 + k0));
        acc0 = __builtin_amdgcn_mfma_f32_16x16x32_bf16(fa, fb0, acc0, 0, 0, 0);
        acc1 = __builtin_amdgcn_mfma_f32_16x16x32_bf16(fa, fb1, acc1, 0, 0, 0);
    }
#pragma unroll
    for (int r = 0; r < 4; ++r) {
        int n = rowbase + lg * 4 + r;
        outf[n * DMODEL + colbase + lr]      = acc0[r];
        outf[n * DMODEL + colbase + 32 + lr] = acc1[r];
    }
}

// ---------------------------------------------------------------------------
extern "C" void kernel_launch(void* const* d_in, const int* in_sizes, int n_in,
                              void* d_out, int out_size, void* d_ws, size_t ws_size,
                              hipStream_t stream) {
    const float* x       = (const float*)d_in[0];
    const float* cache_k = (const float*)d_in[1];
    const float* cache_v = (const float*)d_in[2];
    const int*   ep      = (const int*)  d_in[3];
    const float* Wq      = (const float*)d_in[4];
    const float* Wkv     = (const float*)d_in[5];
    const float* Wg      = (const float*)d_in[6];
    const float* Wo      = (const float*)d_in[7];
    float* out = (float*)d_out;

    u16* u = (u16*)d_ws;
    u16* x_bf    = u;                          // 1048576
    u16* Wt      = x_bf + 1048576;             // 786432
    u16* Wot     = Wt + 786432;                // 262144
    u16* q_bf    = Wot + 262144;               // 1048576
    u16* k_bf    = q_bf + 1048576;             // 1310720
    u16* vT      = k_bf + 1310720;             // 1310720
    u16* attn_bf = vT + 1310720;               // 1048576
    float*  gatesw = (float*)(attn_bf + 1048576);   // 16384 f32
    float2* cs     = (float2*)(gatesw + 16384);     // 81920 float2

    prep<<<448, 256, 0, stream>>>(x, Wq, Wkv, Wo, Wg, cache_v, x_bf, Wt, Wot, gatesw, cs, vT);
    qkv<<<512, 256, 0, stream>>>(x_bf, Wt, cs, cache_k, q_bf, k_bf, vT);
    attn_mfma<<<512, 256, 0, stream>>>(q_bf, k_bf, vT, gatesw, ep, attn_bf);
    outgemm<<<512, 256, 0, stream>>>(attn_bf, Wot, out);
}